// Round 6
// baseline (2604.650 us; speedup 1.0000x reference)
//
#include <hip/hip_runtime.h>

#define CDIM  3072
#define MROWS 8192
#define NOUT  9216
#define NTI   48     // K groups of 64

typedef __bf16 bf16x8 __attribute__((ext_vector_type(8)));
typedef float f32x4 __attribute__((ext_vector_type(4)));
typedef int i32x4 __attribute__((ext_vector_type(4)));

__device__ __forceinline__ unsigned short f2bf(float f) {
  union { float f; unsigned int u; } v; v.f = f;
  unsigned int u = v.u;
  return (unsigned short)((u + 0x7fffu + ((u >> 16) & 1u)) >> 16);  // RNE
}
__device__ __forceinline__ float bfu_lo(unsigned int u) {
  union { unsigned int v; float f; } x; x.v = u << 16; return x.f;
}
__device__ __forceinline__ float bfu_hi(unsigned int u) {
  union { unsigned int v; float f; } x; x.v = u & 0xffff0000u; return x.f;
}
__device__ __forceinline__ void gld16(const void* g, void* l) {
  __builtin_amdgcn_global_load_lds(
      (const __attribute__((address_space(1))) void*)g,
      (__attribute__((address_space(3))) void*)l, 16, 0, 0);
}
__device__ __forceinline__ void gld4(const void* g, void* l) {
  __builtin_amdgcn_global_load_lds(
      (const __attribute__((address_space(1))) void*)g,
      (__attribute__((address_space(3))) void*)l, 4, 0, 0);
}

#define BARRIER() asm volatile("s_barrier" ::: "memory")
#define LGKM0()   asm volatile("s_waitcnt lgkmcnt(0)" ::: "memory")

template<int N> __device__ __forceinline__ void vmw() {
  if constexpr (N == 5)      asm volatile("s_waitcnt vmcnt(5)" ::: "memory");
  else if constexpr (N == 0) asm volatile("s_waitcnt vmcnt(0)" ::: "memory");
}

// ---------------- K1: weight int4-quant -> Bq int8 [9216][3072], sb_t[48][9216],
// Blor bf16 [9216][32] (proj_up)
__global__ __launch_bounds__(256) void k_wquant(const float* __restrict__ w,
                                                const float* __restrict__ pu,
                                                signed char* __restrict__ Bq,
                                                float* __restrict__ sb_t,
                                                unsigned short* __restrict__ Blor) {
  const int row = blockIdx.x;
  const int tid = threadIdx.x;
  #pragma unroll
  for (int it = 0; it < 3; ++it) {
    const int c = it * 1024 + tid * 4;
    const float4 v = *(const float4*)&w[(size_t)row * CDIM + c];
    float am = fmaxf(fmaxf(fabsf(v.x), fabsf(v.y)), fmaxf(fabsf(v.z), fabsf(v.w)));
    #pragma unroll
    for (int off = 1; off < 16; off <<= 1) am = fmaxf(am, __shfl_xor(am, off));
    const float s = fmaxf(am / 7.0f, 1e-8f);                 // IEEE div
    union { signed char c[4]; unsigned int u; } pk;
    pk.c[0] = (signed char)(int)fminf(fmaxf(rintf(v.x / s), -8.f), 7.f);
    pk.c[1] = (signed char)(int)fminf(fmaxf(rintf(v.y / s), -8.f), 7.f);
    pk.c[2] = (signed char)(int)fminf(fmaxf(rintf(v.z / s), -8.f), 7.f);
    pk.c[3] = (signed char)(int)fminf(fmaxf(rintf(v.w / s), -8.f), 7.f);
    *(unsigned int*)&Bq[(size_t)row * CDIM + c] = pk.u;
    if ((tid & 15) == 0) sb_t[(size_t)(it * 16 + (tid >> 4)) * NOUT + row] = s;
  }
  if (tid < 32) Blor[row * 32 + tid] = f2bf(pu[row * 32 + tid]);
}

// ---------------- K2: activation smooth + int4-quant + lora ->
// Aq int8 [8192][3072], sa_t[48][8192], Alor bf16 [8192][32]
__global__ __launch_bounds__(256) void k_aprep(const float* __restrict__ x,
                                               const float* __restrict__ smooth,
                                               const float* __restrict__ pd,
                                               signed char* __restrict__ Aq,
                                               float* __restrict__ sa_t,
                                               unsigned short* __restrict__ Alor) {
  __shared__ unsigned short xsb[4][3072];   // 24 KB
  __shared__ float plds[4][32][33];         // 16.5 KB
  const int tid = threadIdx.x;
  const int w = tid >> 6, l = tid & 63;
  const int row = blockIdx.x * 4 + w;
  const float* xr = x + (size_t)row * CDIM;

  #pragma unroll 2
  for (int it = 0; it < 12; ++it) {
    const int c = it * 256 + l * 4;
    const float4 xv = *(const float4*)&xr[c];
    const float4 sm = *(const float4*)&smooth[c];
    float4 xs;
    xs.x = xv.x / sm.x; xs.y = xv.y / sm.y;   // exact IEEE div
    xs.z = xv.z / sm.z; xs.w = xv.w / sm.w;
    ushort4 xb;
    xb.x = f2bf(xs.x); xb.y = f2bf(xs.y); xb.z = f2bf(xs.z); xb.w = f2bf(xs.w);
    *(ushort4*)&xsb[w][c] = xb;
    float am = fmaxf(fmaxf(fabsf(xs.x), fabsf(xs.y)), fmaxf(fabsf(xs.z), fabsf(xs.w)));
    #pragma unroll
    for (int off = 1; off < 16; off <<= 1) am = fmaxf(am, __shfl_xor(am, off));
    const float s = fmaxf(am / 7.0f, 1e-8f);
    union { signed char c[4]; unsigned int u; } pk;
    pk.c[0] = (signed char)(int)fminf(fmaxf(rintf(xs.x / s), -8.f), 7.f);
    pk.c[1] = (signed char)(int)fminf(fmaxf(rintf(xs.y / s), -8.f), 7.f);
    pk.c[2] = (signed char)(int)fminf(fmaxf(rintf(xs.z / s), -8.f), 7.f);
    pk.c[3] = (signed char)(int)fminf(fmaxf(rintf(xs.w / s), -8.f), 7.f);
    *(unsigned int*)&Aq[(size_t)row * CDIM + c] = pk.u;
    if ((l & 15) == 0) sa_t[(size_t)(it * 4 + (l >> 4)) * MROWS + row] = s;
  }
  __syncthreads();

  // lora: thread (ch=tid>>3 in [0,32), rg=tid&7): c = ch*2 + 64*i (+0,+1)
  const int ch = tid >> 3, rg = tid & 7;
  float acc[4][4] = {};
  for (int i = 0; i < 48; ++i) {
    const int c = ch * 2 + i * 64;
    const float4 p0 = *(const float4*)&pd[(size_t)c * 32 + rg * 4];
    const float4 p1 = *(const float4*)&pd[(size_t)(c + 1) * 32 + rg * 4];
    #pragma unroll
    for (int r4 = 0; r4 < 4; ++r4) {
      const unsigned int u = *(const unsigned int*)&xsb[r4][c];
      const float xa = bfu_lo(u), xb = bfu_hi(u);
      acc[r4][0] += xa * p0.x + xb * p1.x;
      acc[r4][1] += xa * p0.y + xb * p1.y;
      acc[r4][2] += xa * p0.z + xb * p1.z;
      acc[r4][3] += xa * p0.w + xb * p1.w;
    }
  }
  #pragma unroll
  for (int r4 = 0; r4 < 4; ++r4)
    #pragma unroll
    for (int j = 0; j < 4; ++j)
      plds[r4][rg * 4 + j][ch] = acc[r4][j];
  __syncthreads();
  if (tid < 128) {
    const int rr = tid >> 5, r = tid & 31;
    float ssum = 0.f;
    #pragma unroll
    for (int cc = 0; cc < 32; ++cc) ssum += plds[rr][r][cc];
    Alor[(size_t)(blockIdx.x * 4 + rr) * 32 + r] = f2bf(ssum);
  }
}

// ---------------- K3: int8 256x256 GEMM (exact group dot) + lora bf16 pass +
// fused bias/RMSNorm/RoPE epilogue.
// LDS: A slots 0/16K/32K, B slots 48K+..., scale slices 96K+slot*2K (ring 3).
// Row = 64 B, chunk16 swizzle: chunk ^= (row>>1)&3  (uniform 2-way = free).
// vmcnt ledger: 5 loads/window {scaleG,A,A,B,B}; vmw<5> end-ph1 retires
// window t's own... retires g(t+1)-older set; wait distance = 1 window.
__global__ __launch_bounds__(512, 1) void k_gemm8(
    const signed char* __restrict__ Aq, const signed char* __restrict__ Bq,
    const float* __restrict__ sa_t, const float* __restrict__ sb_t,
    const unsigned short* __restrict__ Alor, const unsigned short* __restrict__ Blor,
    const float* __restrict__ bias,
    const float* __restrict__ nqw, const float* __restrict__ nkw,
    const float* __restrict__ fcos, const float* __restrict__ fsin,
    float* __restrict__ outp) {
  __shared__ char ldsc[104448];
  const int tid = threadIdx.x;
  const int w = tid >> 6, l = tid & 63;
  const int wr = w >> 2, wc = w & 3;               // 2M x 4N waves, 128x64 each
  const int l16 = l & 15, g16 = l >> 4;
  // 2D-chunked XCD swizzle (r5)
  const int xcd = blockIdx.x & 7;
  const int jj = blockIdx.x >> 3;
  const int chunk = jj / 36;
  const int tt = jj - chunk * 36;
  const int by = xcd * 4 + tt / 9;
  const int bx = chunk * 9 + tt % 9;
  const int n0 = bx * 256, m0 = by * 256;
  const int arow = wr * 128 + l16;
  const int brow = wc * 64 + l16;
  const int fsb = (g16 ^ ((l16 >> 1) & 3)) << 4;   // frag byte chunk swizzle
  const int rl = tid >> 2;
  const int swz = (tid & 3) ^ ((rl >> 1) & 3);
  const signed char* As0 = Aq + (size_t)(m0 + rl) * CDIM + swz * 16;
  const signed char* As1 = As0 + (size_t)128 * CDIM;
  const signed char* Bs0 = Bq + (size_t)(n0 + rl) * CDIM + swz * 16;
  const signed char* Bs1 = Bs0 + (size_t)128 * CDIM;
  const char* sptr = (tid < 256) ? (const char*)(sa_t + m0 + tid)
                                 : (const char*)(sb_t + n0 + (tid - 256));
  const long long sstep = (tid < 256) ? (long long)MROWS * 4 : (long long)NOUT * 4;

  f32x4 acc[8][4] = {};

  // prologue: {scale,A,B} for g0 -> slot0, g1 -> slot1
  gld4(sptr, ldsc + 98304 + tid * 4);
  gld16(As0, ldsc + tid * 16);                 gld16(As1, ldsc + 8192 + tid * 16);
  gld16(Bs0, ldsc + 49152 + tid * 16);         gld16(Bs1, ldsc + 49152 + 8192 + tid * 16);
  sptr += sstep;
  gld4(sptr, ldsc + 98304 + 2048 + tid * 4);
  gld16(As0 + 64, ldsc + 16384 + tid * 16);    gld16(As1 + 64, ldsc + 16384 + 8192 + tid * 16);
  gld16(Bs0 + 64, ldsc + 49152 + 16384 + tid * 16);
  gld16(Bs1 + 64, ldsc + 49152 + 16384 + 8192 + tid * 16);
  sptr += sstep;
  vmw<5>(); BARRIER();

  int cur = 0, nxt = 2;
  #pragma unroll 1
  for (int t = 0; t < NTI; ++t) {
    const int aoff = cur * 16384, boff = 49152 + cur * 16384, scoff = 98304 + cur * 2048;
    const int soA = nxt * 16384, soB = 49152 + nxt * 16384, soS = 98304 + nxt * 2048;
    f32x4 sa[4]; float sbv[4]; i32x4 av[4], bv[4];
    // ---- ph0: scales + b-frags + a-frags(mi0-3); stage {scale,A}(t+2)
    #pragma unroll
    for (int q = 0; q < 4; ++q)
      sa[q] = *(const f32x4*)(ldsc + scoff + (wr * 128 + q * 16 + g16 * 4) * 4);
    #pragma unroll
    for (int ni = 0; ni < 4; ++ni)
      sbv[ni] = *(const float*)(ldsc + scoff + 1024 + (wc * 64 + ni * 16 + l16) * 4);
    #pragma unroll
    for (int ni = 0; ni < 4; ++ni)
      bv[ni] = *(const i32x4*)(ldsc + boff + (brow + ni * 16) * 64 + fsb);
    #pragma unroll
    for (int mi = 0; mi < 4; ++mi)
      av[mi] = *(const i32x4*)(ldsc + aoff + (arow + mi * 16) * 64 + fsb);
    if (t < NTI - 2) {
      gld4(sptr, ldsc + soS + tid * 4);
      gld16(As0 + (size_t)(t + 2) * 64, ldsc + soA + tid * 16);
      gld16(As1 + (size_t)(t + 2) * 64, ldsc + soA + 8192 + tid * 16);
    } else if (t == NTI - 1) {
      const char* Al0 = (const char*)Alor + (size_t)(m0 + rl) * 64 + swz * 16;
      gld16(Al0, ldsc + soA + tid * 16);
      gld16(Al0 + 128 * 64, ldsc + soA + 8192 + tid * 16);
    }
    BARRIER(); LGKM0();
    __builtin_amdgcn_s_setprio(1);
    {
      i32x4 ia[2][4];
      #pragma unroll
      for (int m2 = 0; m2 < 2; ++m2)
        #pragma unroll
        for (int ni = 0; ni < 4; ++ni)
          ia[m2][ni] = __builtin_amdgcn_mfma_i32_16x16x64_i8(av[m2], bv[ni], (i32x4){0,0,0,0}, 0, 0, 0);
      #pragma unroll
      for (int m2 = 0; m2 < 2; ++m2)
        #pragma unroll
        for (int ni = 0; ni < 4; ++ni)
          acc[m2][ni] += __builtin_convertvector(ia[m2][ni], f32x4) * (sa[m2] * sbv[ni]);
      #pragma unroll
      for (int m2 = 0; m2 < 2; ++m2)
        #pragma unroll
        for (int ni = 0; ni < 4; ++ni)
          ia[m2][ni] = __builtin_amdgcn_mfma_i32_16x16x64_i8(av[2 + m2], bv[ni], (i32x4){0,0,0,0}, 0, 0, 0);
      #pragma unroll
      for (int m2 = 0; m2 < 2; ++m2)
        #pragma unroll
        for (int ni = 0; ni < 4; ++ni)
          acc[2 + m2][ni] += __builtin_convertvector(ia[m2][ni], f32x4) * (sa[2 + m2] * sbv[ni]);
    }
    __builtin_amdgcn_s_setprio(0);
    // ---- ph1: a-frags(mi4-7); stage B(t+2)
    #pragma unroll
    for (int q = 0; q < 4; ++q)
      sa[q] = *(const f32x4*)(ldsc + scoff + (wr * 128 + (q + 4) * 16 + g16 * 4) * 4);
    #pragma unroll
    for (int mi = 0; mi < 4; ++mi)
      av[mi] = *(const i32x4*)(ldsc + aoff + (arow + 64 + mi * 16) * 64 + fsb);
    if (t < NTI - 2) {
      gld16(Bs0 + (size_t)(t + 2) * 64, ldsc + soB + tid * 16);
      gld16(Bs1 + (size_t)(t + 2) * 64, ldsc + soB + 8192 + tid * 16);
      sptr += sstep;
    } else if (t == NTI - 1) {
      const char* Bl0 = (const char*)Blor + (size_t)(n0 + rl) * 64 + swz * 16;
      gld16(Bl0, ldsc + soB + tid * 16);
      gld16(Bl0 + 128 * 64, ldsc + soB + 8192 + tid * 16);
    }
    BARRIER(); LGKM0();
    __builtin_amdgcn_s_setprio(1);
    {
      i32x4 ia[2][4];
      #pragma unroll
      for (int m2 = 0; m2 < 2; ++m2)
        #pragma unroll
        for (int ni = 0; ni < 4; ++ni)
          ia[m2][ni] = __builtin_amdgcn_mfma_i32_16x16x64_i8(av[m2], bv[ni], (i32x4){0,0,0,0}, 0, 0, 0);
      #pragma unroll
      for (int m2 = 0; m2 < 2; ++m2)
        #pragma unroll
        for (int ni = 0; ni < 4; ++ni)
          acc[4 + m2][ni] += __builtin_convertvector(ia[m2][ni], f32x4) * (sa[m2] * sbv[ni]);
      #pragma unroll
      for (int m2 = 0; m2 < 2; ++m2)
        #pragma unroll
        for (int ni = 0; ni < 4; ++ni)
          ia[m2][ni] = __builtin_amdgcn_mfma_i32_16x16x64_i8(av[2 + m2], bv[ni], (i32x4){0,0,0,0}, 0, 0, 0);
      #pragma unroll
      for (int m2 = 0; m2 < 2; ++m2)
        #pragma unroll
        for (int ni = 0; ni < 4; ++ni)
          acc[6 + m2][ni] += __builtin_convertvector(ia[m2][ni], f32x4) * (sa[2 + m2] * sbv[ni]);
    }
    __builtin_amdgcn_s_setprio(0);
    if (t < NTI - 2) { vmw<5>(); } else { vmw<0>(); }
    BARRIER();
    cur = (cur == 2) ? 0 : cur + 1;
    nxt = (nxt == 2) ? 0 : nxt + 1;
  }

  // ---- lora bf16 pass (staged at slot 1 during t=47)
  {
    const int loA = 16384, loB = 49152 + 16384;
    bf16x8 bl[4];
    #pragma unroll
    for (int ni = 0; ni < 4; ++ni)
      bl[ni] = *(const bf16x8*)(ldsc + loB + (brow + ni * 16) * 64 + fsb);
    #pragma unroll
    for (int q = 0; q < 8; ++q) {
      const bf16x8 al = *(const bf16x8*)(ldsc + loA + (arow + q * 16) * 64 + fsb);
      #pragma unroll
      for (int ni = 0; ni < 4; ++ni)
        acc[q][ni] = __builtin_amdgcn_mfma_f32_16x16x32_bf16(al, bl[ni], acc[q][ni], 0, 0, 0);
    }
  }

  // ---------------- fused epilogue (bias -> RMSNorm+RoPE for q/k) ----------------
  float bvv[4];
  #pragma unroll
  for (int ni = 0; ni < 4; ++ni) bvv[ni] = bias[n0 + wc * 64 + ni * 16 + l16];
  #pragma unroll
  for (int q = 0; q < 8; ++q)
    #pragma unroll
    for (int ni = 0; ni < 4; ++ni)
      #pragma unroll
      for (int j = 0; j < 4; ++j) acc[q][ni][j] += bvv[ni];

  if (n0 < 6144) {
    const float* nwt = (n0 < 3072) ? nqw : nkw;
    float nw[4];
    #pragma unroll
    for (int ni = 0; ni < 4; ++ni) nw[ni] = nwt[(wc & 1) * 64 + ni * 16 + l16];

    float part[8][4];
    #pragma unroll
    for (int q = 0; q < 8; ++q)
      #pragma unroll
      for (int j = 0; j < 4; ++j) {
        float ssum = 0.f;
        #pragma unroll
        for (int ni = 0; ni < 4; ++ni) ssum += acc[q][ni][j] * acc[q][ni][j];
        #pragma unroll
        for (int off = 1; off < 16; off <<= 1) ssum += __shfl_xor(ssum, off);
        part[q][j] = ssum;
      }

    __syncthreads();
    float* sq = (float*)ldsc;
    if (l16 == 0) {
      #pragma unroll
      for (int q = 0; q < 8; ++q)
        #pragma unroll
        for (int j = 0; j < 4; ++j) {
          const int r128 = q * 16 + g16 * 4 + j;
          sq[(((wr * 128 + r128) * 2 + (wc >> 1)) * 2) + (wc & 1)] = part[q][j];
        }
    }
    __syncthreads();

    #pragma unroll
    for (int q = 0; q < 8; ++q) {
      #pragma unroll
      for (int j = 0; j < 4; ++j) {
        const int r128 = q * 16 + g16 * 4 + j;
        const float other = sq[(((wr * 128 + r128) * 2 + (wc >> 1)) * 2) + ((wc & 1) ^ 1)];
        const float rinv = 1.0f / sqrtf((part[q][j] + other) * (1.0f / 128.0f) + 1e-6f);
        const int row = m0 + wr * 128 + r128;
        const int sidx = row & 4095;
        #pragma unroll
        for (int ni = 0; ni < 4; ++ni) {
          const int p = (wc & 1) * 32 + ni * 8 + (l16 >> 1);
          const float cv = fcos[(size_t)sidx * 64 + p];
          const float sv = fsin[(size_t)sidx * 64 + p];
          const float v = acc[q][ni][j] * rinv * nw[ni];
          const float o = __shfl_xor(v, 1);
          const float res = ((l & 1) == 0) ? (v * cv - o * sv) : (o * sv + v * cv);
          __builtin_nontemporal_store(res, &outp[(size_t)row * NOUT + n0 + wc * 64 + ni * 16 + l16]);
        }
      }
    }
  } else {
    #pragma unroll
    for (int ni = 0; ni < 4; ++ni) {
      const int gn = n0 + wc * 64 + ni * 16 + l16;
      #pragma unroll
      for (int q = 0; q < 8; ++q) {
        const int gm = m0 + wr * 128 + q * 16 + g16 * 4;
        #pragma unroll
        for (int j = 0; j < 4; ++j)
          __builtin_nontemporal_store(acc[q][ni][j], &outp[(size_t)(gm + j) * NOUT + gn]);
      }
    }
  }
}

extern "C" void kernel_launch(void* const* d_in, const int* in_sizes, int n_in,
                              void* d_out, int out_size, void* d_ws, size_t ws_size,
                              hipStream_t stream) {
  const float* x      = (const float*)d_in[0];
  const float* smooth = (const float*)d_in[1];
  const float* weight = (const float*)d_in[2];
  const float* pd     = (const float*)d_in[3];
  const float* pu     = (const float*)d_in[4];
  const float* bias   = (const float*)d_in[5];
  const float* nqw    = (const float*)d_in[6];
  const float* nkw    = (const float*)d_in[7];
  const float* fcos   = (const float*)d_in[8];
  const float* fsin   = (const float*)d_in[9];
  float* out = (float*)d_out;

  char* ws = (char*)d_ws;
  signed char* Aq   = (signed char*)ws;                       // 25,165,824
  signed char* Bq   = (signed char*)(ws + 25165824);          // 28,311,552
  float* sa_t       = (float*)(ws + 53477376);                // 1,572,864
  float* sb_t       = (float*)(ws + 55050240);                // 1,769,472
  unsigned short* Alor = (unsigned short*)(ws + 56819712);    //   524,288
  unsigned short* Blor = (unsigned short*)(ws + 57344000);    //   589,824

  k_wquant<<<dim3(NOUT), dim3(256), 0, stream>>>(weight, pu, Bq, sb_t, Blor);
  k_aprep<<<dim3(MROWS / 4), dim3(256), 0, stream>>>(x, smooth, pd, Aq, sa_t, Alor);
  k_gemm8<<<dim3(1152), dim3(512), 0, stream>>>(Aq, Bq, sa_t, sb_t, Alor, Blor,
                                                bias, nqw, nkw, fcos, fsin, out);
}

// Round 7
// 578.077 us; speedup vs baseline: 4.5057x; 4.5057x over previous
//
#include <hip/hip_runtime.h>

#define CDIM  3072
#define MROWS 8192
#define NOUT  9216
#define NTI   48     // K groups of 64

typedef __bf16 bf16x8 __attribute__((ext_vector_type(8)));
typedef float f32x4 __attribute__((ext_vector_type(4)));
typedef int i32x4 __attribute__((ext_vector_type(4)));

__device__ __forceinline__ unsigned short f2bf(float f) {
  union { float f; unsigned int u; } v; v.f = f;
  unsigned int u = v.u;
  return (unsigned short)((u + 0x7fffu + ((u >> 16) & 1u)) >> 16);  // RNE
}
__device__ __forceinline__ float bfu_lo(unsigned int u) {
  union { unsigned int v; float f; } x; x.v = u << 16; return x.f;
}
__device__ __forceinline__ float bfu_hi(unsigned int u) {
  union { unsigned int v; float f; } x; x.v = u & 0xffff0000u; return x.f;
}
__device__ __forceinline__ void gld16(const void* g, void* l) {
  __builtin_amdgcn_global_load_lds(
      (const __attribute__((address_space(1))) void*)g,
      (__attribute__((address_space(3))) void*)l, 16, 0, 0);
}
__device__ __forceinline__ void gld4(const void* g, void* l) {
  __builtin_amdgcn_global_load_lds(
      (const __attribute__((address_space(1))) void*)g,
      (__attribute__((address_space(3))) void*)l, 4, 0, 0);
}

#define BARRIER() asm volatile("s_barrier" ::: "memory")

template<int N> __device__ __forceinline__ void vmw() {
  if constexpr (N == 5)      asm volatile("s_waitcnt vmcnt(5)" ::: "memory");
  else if constexpr (N == 0) asm volatile("s_waitcnt vmcnt(0)" ::: "memory");
}

// ---------------- K1: weight int4-quant -> Bq int8 [9216][3072], sb_t[48][9216],
// Blor bf16 [9216][32] (proj_up)
__global__ __launch_bounds__(256) void k_wquant(const float* __restrict__ w,
                                                const float* __restrict__ pu,
                                                signed char* __restrict__ Bq,
                                                float* __restrict__ sb_t,
                                                unsigned short* __restrict__ Blor) {
  const int row = blockIdx.x;
  const int tid = threadIdx.x;
  #pragma unroll
  for (int it = 0; it < 3; ++it) {
    const int c = it * 1024 + tid * 4;
    const float4 v = *(const float4*)&w[(size_t)row * CDIM + c];
    float am = fmaxf(fmaxf(fabsf(v.x), fabsf(v.y)), fmaxf(fabsf(v.z), fabsf(v.w)));
    #pragma unroll
    for (int off = 1; off < 16; off <<= 1) am = fmaxf(am, __shfl_xor(am, off));
    const float s = fmaxf(am / 7.0f, 1e-8f);                 // IEEE div
    union { signed char c[4]; unsigned int u; } pk;
    pk.c[0] = (signed char)(int)fminf(fmaxf(rintf(v.x / s), -8.f), 7.f);
    pk.c[1] = (signed char)(int)fminf(fmaxf(rintf(v.y / s), -8.f), 7.f);
    pk.c[2] = (signed char)(int)fminf(fmaxf(rintf(v.z / s), -8.f), 7.f);
    pk.c[3] = (signed char)(int)fminf(fmaxf(rintf(v.w / s), -8.f), 7.f);
    *(unsigned int*)&Bq[(size_t)row * CDIM + c] = pk.u;
    if ((tid & 15) == 0) sb_t[(size_t)(it * 16 + (tid >> 4)) * NOUT + row] = s;
  }
  if (tid < 32) Blor[row * 32 + tid] = f2bf(pu[row * 32 + tid]);
}

// ---------------- K2: activation smooth + int4-quant + lora ->
// Aq int8 [8192][3072], sa_t[48][8192], Alor bf16 [8192][32]
__global__ __launch_bounds__(256) void k_aprep(const float* __restrict__ x,
                                               const float* __restrict__ smooth,
                                               const float* __restrict__ pd,
                                               signed char* __restrict__ Aq,
                                               float* __restrict__ sa_t,
                                               unsigned short* __restrict__ Alor) {
  __shared__ unsigned short xsb[4][3072];   // 24 KB
  __shared__ float plds[4][32][33];         // 16.5 KB
  const int tid = threadIdx.x;
  const int w = tid >> 6, l = tid & 63;
  const int row = blockIdx.x * 4 + w;
  const float* xr = x + (size_t)row * CDIM;

  #pragma unroll 2
  for (int it = 0; it < 12; ++it) {
    const int c = it * 256 + l * 4;
    const float4 xv = *(const float4*)&xr[c];
    const float4 sm = *(const float4*)&smooth[c];
    float4 xs;
    xs.x = xv.x / sm.x; xs.y = xv.y / sm.y;   // exact IEEE div
    xs.z = xv.z / sm.z; xs.w = xv.w / sm.w;
    ushort4 xb;
    xb.x = f2bf(xs.x); xb.y = f2bf(xs.y); xb.z = f2bf(xs.z); xb.w = f2bf(xs.w);
    *(ushort4*)&xsb[w][c] = xb;
    float am = fmaxf(fmaxf(fabsf(xs.x), fabsf(xs.y)), fmaxf(fabsf(xs.z), fabsf(xs.w)));
    #pragma unroll
    for (int off = 1; off < 16; off <<= 1) am = fmaxf(am, __shfl_xor(am, off));
    const float s = fmaxf(am / 7.0f, 1e-8f);
    union { signed char c[4]; unsigned int u; } pk;
    pk.c[0] = (signed char)(int)fminf(fmaxf(rintf(xs.x / s), -8.f), 7.f);
    pk.c[1] = (signed char)(int)fminf(fmaxf(rintf(xs.y / s), -8.f), 7.f);
    pk.c[2] = (signed char)(int)fminf(fmaxf(rintf(xs.z / s), -8.f), 7.f);
    pk.c[3] = (signed char)(int)fminf(fmaxf(rintf(xs.w / s), -8.f), 7.f);
    *(unsigned int*)&Aq[(size_t)row * CDIM + c] = pk.u;
    if ((l & 15) == 0) sa_t[(size_t)(it * 4 + (l >> 4)) * MROWS + row] = s;
  }
  __syncthreads();

  const int ch = tid >> 3, rg = tid & 7;
  float acc[4][4] = {};
  for (int i = 0; i < 48; ++i) {
    const int c = ch * 2 + i * 64;
    const float4 p0 = *(const float4*)&pd[(size_t)c * 32 + rg * 4];
    const float4 p1 = *(const float4*)&pd[(size_t)(c + 1) * 32 + rg * 4];
    #pragma unroll
    for (int r4 = 0; r4 < 4; ++r4) {
      const unsigned int u = *(const unsigned int*)&xsb[r4][c];
      const float xa = bfu_lo(u), xb = bfu_hi(u);
      acc[r4][0] += xa * p0.x + xb * p1.x;
      acc[r4][1] += xa * p0.y + xb * p1.y;
      acc[r4][2] += xa * p0.z + xb * p1.z;
      acc[r4][3] += xa * p0.w + xb * p1.w;
    }
  }
  #pragma unroll
  for (int r4 = 0; r4 < 4; ++r4)
    #pragma unroll
    for (int j = 0; j < 4; ++j)
      plds[r4][rg * 4 + j][ch] = acc[r4][j];
  __syncthreads();
  if (tid < 128) {
    const int rr = tid >> 5, r = tid & 31;
    float ssum = 0.f;
    #pragma unroll
    for (int cc = 0; cc < 32; ++cc) ssum += plds[rr][r][cc];
    Alor[(size_t)(blockIdx.x * 4 + rr) * 32 + r] = f2bf(ssum);
  }
}

// ---------------- K3: int8 128x128 GEMM (exact group dots), 4 waves, 64x64/wave.
// LDS per buf (17408 B): A[128][64]i8 @0, B[128][64]i8 @8192, scales @16384
// (sa[128] f32, sb[128] f32). Double-buffered. 5 loads/thread/group
// {S,A,A,B,B}; vmcnt(5) waits exactly the previous group's set (1-window
// distance). 16B-chunk swizzle: chunk ^= (row>>1)&3 (measured 0-conflict).
__global__ __launch_bounds__(256, 2) void k_gemmi8(
    const signed char* __restrict__ Aq, const signed char* __restrict__ Bq,
    const float* __restrict__ sa_t, const float* __restrict__ sb_t,
    const unsigned short* __restrict__ Alor, const unsigned short* __restrict__ Blor,
    const float* __restrict__ bias,
    const float* __restrict__ nqw, const float* __restrict__ nkw,
    const float* __restrict__ fcos, const float* __restrict__ fsin,
    float* __restrict__ outp) {
  __shared__ char lds[34816];
  const int tid = threadIdx.x;
  const int w = tid >> 6, l = tid & 63;
  const int wm = w >> 1, wn = w & 1;          // 2x2 waves, 64x64 each
  const int l16 = l & 15, g16 = l >> 4;
  // XCD swizzle: xcd owns by-band [8*xcd,8*xcd+8), swept in 4-by x 9-bx chunks
  const int xcd = blockIdx.x & 7;
  const int j = blockIdx.x >> 3;              // 0..575
  const int chunk = j / 36;                   // 0..15
  const int t = j - chunk * 36;               // 0..35
  const int by = xcd * 8 + (chunk & 1) * 4 + t / 9;
  const int bx = (chunk >> 1) * 9 + t % 9;
  const int m0 = by * 128, n0 = bx * 128;
  const int fsb = (g16 ^ ((l16 >> 1) & 3)) << 4;
  // staging: rows rl and rl+64, 16B chunk (tid&3), pre-swizzled source
  const int rl = tid >> 2;
  const int swz = (((tid & 3) ^ ((rl >> 1) & 3)) << 4);
  const signed char* As0 = Aq + (size_t)(m0 + rl) * CDIM + swz;
  const signed char* As1 = As0 + (size_t)64 * CDIM;
  const signed char* Bs0 = Bq + (size_t)(n0 + rl) * CDIM + swz;
  const signed char* Bs1 = Bs0 + (size_t)64 * CDIM;
  const char* sptr = (tid < 128) ? (const char*)(sa_t + m0 + tid)
                                 : (const char*)(sb_t + n0 + (tid - 128));
  const long long sstep = (tid < 128) ? (long long)MROWS * 4 : (long long)NOUT * 4;

  f32x4 acc[4][4] = {};

  // prologue: stage group 0 into buf0
  gld4(sptr, lds + 16384 + tid * 4); sptr += sstep;
  gld16(As0, lds + tid * 16);            gld16(As1, lds + 4096 + tid * 16);
  gld16(Bs0, lds + 8192 + tid * 16);     gld16(Bs1, lds + 8192 + 4096 + tid * 16);

  #pragma unroll 1
  for (int g = 0; g < NTI; ++g) {
    const int cb = (g & 1) * 17408;           // current buf
    const int nb = ((g + 1) & 1) * 17408;     // next buf
    if (g < NTI - 1) {
      const size_t kc = (size_t)(g + 1) * 64;
      gld4(sptr, lds + nb + 16384 + tid * 4); sptr += sstep;
      gld16(As0 + kc, lds + nb + tid * 16);
      gld16(As1 + kc, lds + nb + 4096 + tid * 16);
      gld16(Bs0 + kc, lds + nb + 8192 + tid * 16);
      gld16(Bs1 + kc, lds + nb + 8192 + 4096 + tid * 16);
      vmw<5>();
    } else {
      vmw<0>();
    }
    BARRIER();
    f32x4 sa[4]; float sbv[4]; i32x4 av[4], bv[4];
    #pragma unroll
    for (int mi = 0; mi < 4; ++mi)
      sa[mi] = *(const f32x4*)(lds + cb + 16384 + (wm * 64 + mi * 16 + g16 * 4) * 4);
    #pragma unroll
    for (int ni = 0; ni < 4; ++ni)
      sbv[ni] = *(const float*)(lds + cb + 16896 + (wn * 64 + ni * 16 + l16) * 4);
    #pragma unroll
    for (int mi = 0; mi < 4; ++mi)
      av[mi] = *(const i32x4*)(lds + cb + (wm * 64 + mi * 16 + l16) * 64 + fsb);
    #pragma unroll
    for (int ni = 0; ni < 4; ++ni)
      bv[ni] = *(const i32x4*)(lds + cb + 8192 + (wn * 64 + ni * 16 + l16) * 64 + fsb);
    __builtin_amdgcn_s_setprio(1);
    #pragma unroll
    for (int mi = 0; mi < 4; ++mi) {
      i32x4 ia[4];
      #pragma unroll
      for (int ni = 0; ni < 4; ++ni)
        ia[ni] = __builtin_amdgcn_mfma_i32_16x16x64_i8(av[mi], bv[ni], (i32x4){0,0,0,0}, 0, 0, 0);
      #pragma unroll
      for (int ni = 0; ni < 4; ++ni)
        acc[mi][ni] += __builtin_convertvector(ia[ni], f32x4) * (sa[mi] * sbv[ni]);
    }
    __builtin_amdgcn_s_setprio(0);
    BARRIER();
  }

  // ---- lora bf16 pass: stage Alor/Blor rows into buf0 (64B rows, same swizzle)
  {
    const char* Al0 = (const char*)Alor + (size_t)(m0 + rl) * 64 + swz;
    const char* Bl0 = (const char*)Blor + (size_t)(n0 + rl) * 64 + swz;
    gld16(Al0, lds + tid * 16);            gld16(Al0 + 64 * 64, lds + 4096 + tid * 16);
    gld16(Bl0, lds + 8192 + tid * 16);     gld16(Bl0 + 64 * 64, lds + 8192 + 4096 + tid * 16);
    vmw<0>(); BARRIER();
    bf16x8 bl[4];
    #pragma unroll
    for (int ni = 0; ni < 4; ++ni)
      bl[ni] = *(const bf16x8*)(lds + 8192 + (wn * 64 + ni * 16 + l16) * 64 + fsb);
    #pragma unroll
    for (int mi = 0; mi < 4; ++mi) {
      const bf16x8 al = *(const bf16x8*)(lds + (wm * 64 + mi * 16 + l16) * 64 + fsb);
      #pragma unroll
      for (int ni = 0; ni < 4; ++ni)
        acc[mi][ni] = __builtin_amdgcn_mfma_f32_16x16x32_bf16(al, bl[ni], acc[mi][ni], 0, 0, 0);
    }
  }

  // ---------------- fused epilogue (bias -> RMSNorm+RoPE for q/k) ----------------
  float bvv[4];
  #pragma unroll
  for (int ni = 0; ni < 4; ++ni) bvv[ni] = bias[n0 + wn * 64 + ni * 16 + l16];
  #pragma unroll
  for (int mi = 0; mi < 4; ++mi)
    #pragma unroll
    for (int ni = 0; ni < 4; ++ni)
      #pragma unroll
      for (int jj = 0; jj < 4; ++jj) acc[mi][ni][jj] += bvv[ni];

  if (n0 < 6144) {
    const float* nwt = (n0 < 3072) ? nqw : nkw;
    float nw[4];
    #pragma unroll
    for (int ni = 0; ni < 4; ++ni) nw[ni] = nwt[wn * 64 + ni * 16 + l16];

    float part[4][4];
    #pragma unroll
    for (int mi = 0; mi < 4; ++mi)
      #pragma unroll
      for (int jj = 0; jj < 4; ++jj) {
        float ssum = 0.f;
        #pragma unroll
        for (int ni = 0; ni < 4; ++ni) ssum += acc[mi][ni][jj] * acc[mi][ni][jj];
        #pragma unroll
        for (int off = 1; off < 16; off <<= 1) ssum += __shfl_xor(ssum, off);
        part[mi][jj] = ssum;   // partial over this wave's 64 cols (row fixed)
      }

    __syncthreads();
    float* sq = (float*)lds;   // [128 rows][2 col-waves]
    if (l16 == 0) {
      #pragma unroll
      for (int mi = 0; mi < 4; ++mi)
        #pragma unroll
        for (int jj = 0; jj < 4; ++jj)
          sq[(wm * 64 + mi * 16 + g16 * 4 + jj) * 2 + wn] = part[mi][jj];
    }
    __syncthreads();

    #pragma unroll
    for (int mi = 0; mi < 4; ++mi) {
      #pragma unroll
      for (int jj = 0; jj < 4; ++jj) {
        const int r128 = wm * 64 + mi * 16 + g16 * 4 + jj;
        const float other = sq[r128 * 2 + (wn ^ 1)];
        const float rinv = 1.0f / sqrtf((part[mi][jj] + other) * (1.0f / 128.0f) + 1e-6f);
        const int row = m0 + r128;
        const int sidx = row & 4095;
        #pragma unroll
        for (int ni = 0; ni < 4; ++ni) {
          const int p = wn * 32 + ni * 8 + (l16 >> 1);
          const float cv = fcos[(size_t)sidx * 64 + p];
          const float sv = fsin[(size_t)sidx * 64 + p];
          const float v = acc[mi][ni][jj] * rinv * nw[ni];
          const float o = __shfl_xor(v, 1);
          const float res = ((l & 1) == 0) ? (v * cv - o * sv) : (o * sv + v * cv);
          __builtin_nontemporal_store(res, &outp[(size_t)row * NOUT + n0 + wn * 64 + ni * 16 + l16]);
        }
      }
    }
  } else {
    #pragma unroll
    for (int ni = 0; ni < 4; ++ni) {
      const int gn = n0 + wn * 64 + ni * 16 + l16;
      #pragma unroll
      for (int mi = 0; mi < 4; ++mi) {
        const int gm = m0 + wm * 64 + mi * 16 + g16 * 4;
        #pragma unroll
        for (int jj = 0; jj < 4; ++jj)
          __builtin_nontemporal_store(acc[mi][ni][jj], &outp[(size_t)(gm + jj) * NOUT + gn]);
      }
    }
  }
}

extern "C" void kernel_launch(void* const* d_in, const int* in_sizes, int n_in,
                              void* d_out, int out_size, void* d_ws, size_t ws_size,
                              hipStream_t stream) {
  const float* x      = (const float*)d_in[0];
  const float* smooth = (const float*)d_in[1];
  const float* weight = (const float*)d_in[2];
  const float* pd     = (const float*)d_in[3];
  const float* pu     = (const float*)d_in[4];
  const float* bias   = (const float*)d_in[5];
  const float* nqw    = (const float*)d_in[6];
  const float* nkw    = (const float*)d_in[7];
  const float* fcos   = (const float*)d_in[8];
  const float* fsin   = (const float*)d_in[9];
  float* out = (float*)d_out;

  char* ws = (char*)d_ws;
  signed char* Aq   = (signed char*)ws;                       // 25,165,824
  signed char* Bq   = (signed char*)(ws + 25165824);          // 28,311,552
  float* sa_t       = (float*)(ws + 53477376);                // 1,572,864
  float* sb_t       = (float*)(ws + 55050240);                // 1,769,472
  unsigned short* Alor = (unsigned short*)(ws + 56819712);    //   524,288
  unsigned short* Blor = (unsigned short*)(ws + 57344000);    //   589,824

  k_wquant<<<dim3(NOUT), dim3(256), 0, stream>>>(weight, pu, Bq, sb_t, Blor);
  k_aprep<<<dim3(MROWS / 4), dim3(256), 0, stream>>>(x, smooth, pd, Aq, sa_t, Alor);
  k_gemmi8<<<dim3(4608), dim3(256), 0, stream>>>(Aq, Bq, sa_t, sb_t, Alor, Blor,
                                                 bias, nqw, nkw, fcos, fsin, out);
}